// Round 9
// baseline (349.437 us; speedup 1.0000x reference)
//
#include <hip/hip_runtime.h>
#include <math.h>

typedef float f32x4 __attribute__((ext_vector_type(4)));
typedef short s16x8 __attribute__((ext_vector_type(8)));
typedef short s16x4 __attribute__((ext_vector_type(4)));

__device__ __forceinline__ short f2bf(float f) {
    unsigned u = __builtin_bit_cast(unsigned, f);
    unsigned r = u + 0x7FFFu + ((u >> 16) & 1u);
    return (short)(r >> 16);
}
__device__ __forceinline__ float bf2f(short h) {
    return __builtin_bit_cast(float, ((unsigned)(unsigned short)h) << 16);
}
__device__ __forceinline__ unsigned pack2(short a, short b) {
    return (unsigned)(unsigned short)a | ((unsigned)(unsigned short)b << 16);
}

__device__ __forceinline__ void split16(const float* __restrict__ p,
                                        short* hi, short* lo) {
    f32x4 a0 = *(const f32x4*)(p);
    f32x4 a1 = *(const f32x4*)(p + 4);
    f32x4 a2 = *(const f32x4*)(p + 8);
    f32x4 a3 = *(const f32x4*)(p + 12);
    s16x8 h0, h1, l0, l1;
    #pragma unroll
    for (int i = 0; i < 4; ++i) {
        short h;
        h = f2bf(a0[i]); h0[i]     = h; l0[i]     = f2bf(a0[i] - bf2f(h));
        h = f2bf(a1[i]); h0[4 + i] = h; l0[4 + i] = f2bf(a1[i] - bf2f(h));
        h = f2bf(a2[i]); h1[i]     = h; l1[i]     = f2bf(a2[i] - bf2f(h));
        h = f2bf(a3[i]); h1[4 + i] = h; l1[4 + i] = f2bf(a3[i] - bf2f(h));
    }
    *(s16x8*)hi       = h0;
    *(s16x8*)(hi + 8) = h1;
    *(s16x8*)lo       = l0;
    *(s16x8*)(lo + 8) = l1;
}

// ---------------------------------------------------------------------------
// Pre-split 5 weight matrices AND the 3 activation inputs into hi/lo bf16.
// ---------------------------------------------------------------------------
__global__ __launch_bounds__(256) void presplit_kernel(
    const float* __restrict__ W0, const float* __restrict__ W1,
    const float* __restrict__ W2, const float* __restrict__ W3,
    const float* __restrict__ W4,
    const float* __restrict__ X0, const float* __restrict__ X1,
    const float* __restrict__ X2,
    short* __restrict__ Wsp, short* __restrict__ Xsp)
{
    const int blk = blockIdx.x;
    if (blk < 320) {
        const int w = blk >> 6, bi = blk & 63;
        const float* src = (w == 0) ? W0 : (w == 1) ? W1 : (w == 2) ? W2
                          : (w == 3) ? W3 : W4;
        short* hi = Wsp + (long)w * 524288;
        short* lo = hi + 262144;
        const int idx = (bi * 256 + threadIdx.x) * 16;
        split16(src + idx, hi + idx, lo + idx);
    } else {
        const int b2 = blk - 320;
        const int x = b2 >> 9, bi = b2 & 511;
        const float* src = (x == 0) ? X0 : (x == 1) ? X1 : X2;
        short* hi = Xsp + (long)x * 4194304;
        short* lo = hi + 2097152;
        const int idx = (bi * 256 + threadIdx.x) * 16;
        split16(src + idx, hi + idx, lo + idx);
    }
}

// ---------------------------------------------------------------------------
// Fused Q/K/V/G projections. NO LDS staging, NO main-loop barriers: MFMA
// fragments loaded directly global->VGPR (layout matches lane=row, quad*8=k).
// 64x128 tile, 4 waves 2x2 (wave 32x64), BK=32.
// mode 0: Q rotary -> split [B,H,N,D]; 1: K rotary*0.125 -> hi [B,H,N,D];
// mode 2: V -> hi TRANSPOSED [B,H,D,N]; 3: G silu -> fp32 [B,N,E]
// ---------------------------------------------------------------------------
__global__ __launch_bounds__(256, 2) void projqkvg_kernel(
    const short* __restrict__ Xsp, const short* __restrict__ Wsp,
    const float* __restrict__ bq, const float* __restrict__ bk,
    const float* __restrict__ bv, const float* __restrict__ bg,
    short* __restrict__ Qh, short* __restrict__ Ql,
    short* __restrict__ Kh, short* __restrict__ Vth,
    float* __restrict__ G)
{
    __shared__ __align__(16) short SB[9216];   // epilogue assembly only

    const int mode = blockIdx.z;
    const int xi = (mode == 1) ? 1 : (mode == 2) ? 2 : 0;
    const short* Xh_g = Xsp + (long)xi * 4194304;
    const short* Xl_g = Xh_g + 2097152;
    const short* Wh_g = Wsp + (long)mode * 524288;
    const short* Wl_g = Wh_g + 262144;
    const float* bias = (mode == 0) ? bq : (mode == 1) ? bk
                       : (mode == 2) ? bv : bg;

    const int t = threadIdx.x, lane = t & 63, wv = t >> 6;
    const int wm = wv >> 1, wn = wv & 1;
    const int quad = lane >> 4, l15 = lane & 15;
    const int m0 = blockIdx.y * 64, n0 = blockIdx.x * 128;

    f32x4 acc[2][4];
    #pragma unroll
    for (int i = 0; i < 2; ++i)
        #pragma unroll
        for (int j = 0; j < 4; ++j)
            acc[i][j] = (f32x4){0.f, 0.f, 0.f, 0.f};

    const long abase0 = (long)(m0 + wm * 32 + l15) * 512 + quad * 8;
    const long abase1 = abase0 + 16 * 512;
    const long bbase = (long)(n0 + wn * 64 + l15) * 512 + quad * 8;

    #pragma unroll 2
    for (int k0 = 0; k0 < 512; k0 += 32) {
        s16x8 ah[2], al[2], bh[4], bl[4];
        ah[0] = *(const s16x8*)(Xh_g + abase0 + k0);
        ah[1] = *(const s16x8*)(Xh_g + abase1 + k0);
        al[0] = *(const s16x8*)(Xl_g + abase0 + k0);
        al[1] = *(const s16x8*)(Xl_g + abase1 + k0);
        #pragma unroll
        for (int s = 0; s < 4; ++s) {
            bh[s] = *(const s16x8*)(Wh_g + bbase + s * 16 * 512 + k0);
            bl[s] = *(const s16x8*)(Wl_g + bbase + s * 16 * 512 + k0);
        }
        #pragma unroll
        for (int i = 0; i < 2; ++i)
            #pragma unroll
            for (int j = 0; j < 4; ++j) {
                acc[i][j] = __builtin_amdgcn_mfma_f32_16x16x32_bf16(ah[i], bh[j], acc[i][j], 0, 0, 0);
                acc[i][j] = __builtin_amdgcn_mfma_f32_16x16x32_bf16(al[i], bh[j], acc[i][j], 0, 0, 0);
                acc[i][j] = __builtin_amdgcn_mfma_f32_16x16x32_bf16(ah[i], bl[j], acc[i][j], 0, 0, 0);
            }
    }

    const int bb = m0 >> 11, posb = m0 & 2047;

    if (mode == 0) {
        short* Thi = SB + wv * 2304;
        short* Tlo = Thi + 1152;
        const int hcol = (n0 >> 6) + wn;
        #pragma unroll
        for (int ms = 0; ms < 2; ++ms) {
            #pragma unroll
            for (int ns = 0; ns < 4; ++ns) {
                const int col = n0 + wn * 64 + ns * 16 + l15;
                const float bvv = bias[col];
                const int pp = (col & 63) >> 1;
                const float theta = powf(10000.0f, -(float)pp * (1.0f / 31.0f));
                #pragma unroll
                for (int r = 0; r < 4; ++r) {
                    const int m = m0 + wm * 32 + ms * 16 + quad * 4 + r;
                    const int pos = m & 2047;
                    float x = acc[ms][ns][r] + bvv;
                    float prt = __shfl_xor(x, 1);
                    float ang = (float)pos * theta;
                    float sv = sinf(ang), cv = cosf(ang);
                    float y0 = x * cv - prt * sv;
                    float y1 = prt * cv + x * sv;
                    if (!(l15 & 1)) {
                        short h0 = f2bf(y0), h1 = f2bf(y1);
                        short l0 = f2bf(y0 - bf2f(h0)), l1 = f2bf(y1 - bf2f(h1));
                        const int o = (quad * 4 + r) * 72 + ns * 16 + l15;
                        *(unsigned*)&Thi[o] = pack2(h0, h1);
                        *(unsigned*)&Tlo[o] = pack2(l0, l1);
                    }
                }
            }
            const int mrow = wm * 32 + ms * 16;
            #pragma unroll
            for (int p2 = 0; p2 < 2; ++p2) {
                const int row = p2 * 8 + (lane >> 3);
                const int ch = (lane & 7) * 8;
                s16x8 vh = *(const s16x8*)&Thi[row * 72 + ch];
                s16x8 vl = *(const s16x8*)&Tlo[row * 72 + ch];
                const long o = ((long)(bb * 8 + hcol) * 2048 + posb + mrow + row) * 64 + ch;
                *(s16x8*)(Qh + o) = vh;
                *(s16x8*)(Ql + o) = vl;
            }
        }
    } else if (mode == 1) {
        short* Thi = SB + wv * 1152;
        const int hcol = (n0 >> 6) + wn;
        #pragma unroll
        for (int ms = 0; ms < 2; ++ms) {
            #pragma unroll
            for (int ns = 0; ns < 4; ++ns) {
                const int col = n0 + wn * 64 + ns * 16 + l15;
                const float bvv = bias[col];
                const int pp = (col & 63) >> 1;
                const float theta = powf(10000.0f, -(float)pp * (1.0f / 31.0f));
                #pragma unroll
                for (int r = 0; r < 4; ++r) {
                    const int m = m0 + wm * 32 + ms * 16 + quad * 4 + r;
                    const int pos = m & 2047;
                    float x = acc[ms][ns][r] + bvv;
                    float prt = __shfl_xor(x, 1);
                    float ang = (float)pos * theta;
                    float sv = sinf(ang), cv = cosf(ang);
                    float y0 = (x * cv - prt * sv) * 0.125f;
                    float y1 = (prt * cv + x * sv) * 0.125f;
                    if (!(l15 & 1)) {
                        const int o = (quad * 4 + r) * 72 + ns * 16 + l15;
                        *(unsigned*)&Thi[o] = pack2(f2bf(y0), f2bf(y1));
                    }
                }
            }
            const int mrow = wm * 32 + ms * 16;
            #pragma unroll
            for (int p2 = 0; p2 < 2; ++p2) {
                const int row = p2 * 8 + (lane >> 3);
                const int ch = (lane & 7) * 8;
                s16x8 vh = *(const s16x8*)&Thi[row * 72 + ch];
                const long o = ((long)(bb * 8 + hcol) * 2048 + posb + mrow + row) * 64 + ch;
                *(s16x8*)(Kh + o) = vh;
            }
        }
    } else if (mode == 2) {
        short* T2 = SB;   // 128 x 72
        #pragma unroll
        for (int ns = 0; ns < 4; ++ns) {
            const int col = n0 + wn * 64 + ns * 16 + l15;
            const float bvv = bias[col];
            #pragma unroll
            for (int ms = 0; ms < 2; ++ms) {
                s16x4 pk;
                #pragma unroll
                for (int r = 0; r < 4; ++r)
                    pk[r] = f2bf(acc[ms][ns][r] + bvv);
                *(s16x4*)&T2[(wn * 64 + ns * 16 + l15) * 72
                             + wm * 32 + ms * 16 + quad * 4] = pk;
            }
        }
        __syncthreads();
        #pragma unroll
        for (int pass = 0; pass < 4; ++pass) {
            const int row = pass * 32 + (t >> 3);
            const int ch = (t & 7) * 8;
            s16x8 v = *(const s16x8*)&T2[row * 72 + ch];
            const int head = (n0 >> 6) + (row >> 6);
            const int d = row & 63;
            const long o = ((long)(bb * 8 + head) * 64 + d) * 2048 + posb + ch;
            *(s16x8*)(Vth + o) = v;
        }
    } else {
        #pragma unroll
        for (int ns = 0; ns < 4; ++ns) {
            const int col = n0 + wn * 64 + ns * 16 + l15;
            const float bvv = bias[col];
            #pragma unroll
            for (int ms = 0; ms < 2; ++ms)
                #pragma unroll
                for (int r = 0; r < 4; ++r) {
                    const int m = m0 + wm * 32 + ms * 16 + quad * 4 + r;
                    float x = acc[ms][ns][r] + bvv;
                    G[(long)m * 512 + col] = x / (1.0f + expf(-x));
                }
        }
    }
}

// ---------------------------------------------------------------------------
// Retention attention. K,V,P bf16 hi; Q split. NO K/V LDS staging, NO
// barriers: fragments loaded directly from global, phase-overlapped reload
// (K reloaded during PV, V reloaded after PV). P via wave-private LDS.
// ---------------------------------------------------------------------------
__global__ __launch_bounds__(256, 2) void attn_kernel(
    const short* __restrict__ Qh_g, const short* __restrict__ Ql_g,
    const short* __restrict__ Kh_g, const short* __restrict__ Vth_g,
    const float* __restrict__ G,
    short* __restrict__ RGh)
{
    __shared__ __align__(16) short PS[4 * 1152];

    const int t = threadIdx.x, lane = t & 63, wv = t >> 6;
    const int quad = lane >> 4, l15 = lane & 15;
    const int bh = blockIdx.y, h = bh & 7, b = bh >> 3;
    const int qt = (bh & 1) ? blockIdx.x : (31 - blockIdx.x);
    const int n0 = qt * 64;
    const long base = (long)bh * 2048 * 64;
    short* Pw = &PS[wv * 1152];

    float l2g;
    int stLo;
    {
        float lg0 = logf(1.0f / 32.0f), lg1 = logf(1.0f / 512.0f);
        float om = expf(lg0 + (float)h * (lg1 - lg0) * (1.0f / 7.0f));
        l2g = log2f(1.0f - om);
        int Dcut = (int)(11.5129255f / om) + 64;
        stLo = (n0 - Dcut) >> 6;
        if (stLo < 0) stLo = 0;
    }
    float gneg[16];
    #pragma unroll
    for (int i = 0; i < 16; ++i)
        gneg[i] = exp2f(-(float)((i >> 2) * 16 + (i & 3)) * l2g);

    const int n = n0 + wv * 16 + l15;

    s16x8 qh[2], ql[2];
    {
        const long qo = base + (long)(n0 + wv * 16 + l15) * 64 + quad * 8;
        qh[0] = *(const s16x8*)(Qh_g + qo);
        qh[1] = *(const s16x8*)(Qh_g + qo + 32);
        ql[0] = *(const s16x8*)(Ql_g + qo);
        ql[1] = *(const s16x8*)(Ql_g + qo + 32);
    }

    f32x4 racc[4];
    #pragma unroll
    for (int i = 0; i < 4; ++i) racc[i] = (f32x4){0.f, 0.f, 0.f, 0.f};

    // fragment base addresses (k-frag: lane=s-row; v-frag: lane=d-row)
    const long kfb = base + (long)l15 * 64 + quad * 8;        // + (s0+sub*16)*64
    const long vfb = base + (long)l15 * 2048 + quad * 8;      // + ds*16*2048 + s0

    s16x8 pk[8], pv[8];
    {
        const long s0 = (long)stLo * 64;
        #pragma unroll
        for (int sub = 0; sub < 4; ++sub) {
            const long o = kfb + (s0 + sub * 16) * 64;
            pk[sub * 2]     = *(const s16x8*)(Kh_g + o);
            pk[sub * 2 + 1] = *(const s16x8*)(Kh_g + o + 32);
        }
        #pragma unroll
        for (int ds = 0; ds < 4; ++ds) {
            const long o = vfb + (long)ds * 16 * 2048 + s0;
            pv[ds * 2]     = *(const s16x8*)(Vth_g + o);
            pv[ds * 2 + 1] = *(const s16x8*)(Vth_g + o + 32);
        }
    }

    for (int st = stLo; st <= qt; ++st) {
        const int s0 = st * 64;
        const float t0 = exp2f((float)(n - s0 - quad * 4) * l2g);

        // QK phase (consumes pk)
        #pragma unroll
        for (int sub = 0; sub < 4; ++sub) {
            f32x4 sacc = (f32x4){0.f, 0.f, 0.f, 0.f};
            sacc = __builtin_amdgcn_mfma_f32_16x16x32_bf16(pk[sub * 2],     qh[0], sacc, 0, 0, 0);
            sacc = __builtin_amdgcn_mfma_f32_16x16x32_bf16(pk[sub * 2 + 1], qh[1], sacc, 0, 0, 0);
            sacc = __builtin_amdgcn_mfma_f32_16x16x32_bf16(pk[sub * 2],     ql[0], sacc, 0, 0, 0);
            sacc = __builtin_amdgcn_mfma_f32_16x16x32_bf16(pk[sub * 2 + 1], ql[1], sacc, 0, 0, 0);

            const int sb = s0 + sub * 16 + quad * 4;
            s16x4 pkh;
            #pragma unroll
            for (int r = 0; r < 4; ++r) {
                const int s = sb + r;
                const float wgt = (n >= s) ? t0 * gneg[sub * 4 + r] : 0.0f;
                pkh[r] = f2bf(sacc[r] * wgt);
            }
            *(s16x4*)&Pw[l15 * 68 + sub * 16 + quad * 4] = pkh;
        }

        // reload K for next tile (overlaps PV)
        if (st < qt) {
            const long s1 = (long)(s0 + 64);
            #pragma unroll
            for (int sub = 0; sub < 4; ++sub) {
                const long o = kfb + (s1 + sub * 16) * 64;
                pk[sub * 2]     = *(const s16x8*)(Kh_g + o);
                pk[sub * 2 + 1] = *(const s16x8*)(Kh_g + o + 32);
            }
        }

        // PV phase (consumes pv)
        s16x8 ph0 = *(const s16x8*)&Pw[l15 * 68 + quad * 8];
        s16x8 ph1 = *(const s16x8*)&Pw[l15 * 68 + quad * 8 + 32];
        #pragma unroll
        for (int ds = 0; ds < 4; ++ds) {
            racc[ds] = __builtin_amdgcn_mfma_f32_16x16x32_bf16(ph0, pv[ds * 2],     racc[ds], 0, 0, 0);
            racc[ds] = __builtin_amdgcn_mfma_f32_16x16x32_bf16(ph1, pv[ds * 2 + 1], racc[ds], 0, 0, 0);
        }

        // reload V for next tile (overlaps next QK)
        if (st < qt) {
            const long s1 = (long)(s0 + 64);
            #pragma unroll
            for (int ds = 0; ds < 4; ++ds) {
                const long o = vfb + (long)ds * 16 * 2048 + s1;
                pv[ds * 2]     = *(const s16x8*)(Vth_g + o);
                pv[ds * 2 + 1] = *(const s16x8*)(Vth_g + o + 32);
            }
        }
    }

    float mean[4], rstd[4];
    #pragma unroll
    for (int r = 0; r < 4; ++r) {
        float s = racc[0][r] + racc[1][r] + racc[2][r] + racc[3][r];
        s += __shfl_xor(s, 1); s += __shfl_xor(s, 2);
        s += __shfl_xor(s, 4); s += __shfl_xor(s, 8);
        mean[r] = s * (1.0f / 64.0f);
        float vs = 0.f;
        #pragma unroll
        for (int ds = 0; ds < 4; ++ds) {
            float d = racc[ds][r] - mean[r];
            vs += d * d;
        }
        vs += __shfl_xor(vs, 1); vs += __shfl_xor(vs, 2);
        vs += __shfl_xor(vs, 4); vs += __shfl_xor(vs, 8);
        rstd[r] = rsqrtf(vs * (1.0f / 64.0f) + 1e-6f);
    }

    // per-wave RG assembly (reuse Pw, in-order DS, no barrier)
    #pragma unroll
    for (int ds = 0; ds < 4; ++ds) {
        #pragma unroll
        for (int r = 0; r < 4; ++r) {
            const int nn = n0 + wv * 16 + quad * 4 + r;
            const int d = ds * 16 + l15;
            const long gi = ((long)(b * 2048 + nn)) * 512 + h * 64 + d;
            float rg = (racc[ds][r] - mean[r]) * rstd[r] * G[gi];
            float prt = __shfl_xor(rg, 1);
            if (!(l15 & 1)) {
                const int o = (quad * 4 + r) * 72 + ds * 16 + l15;
                *(unsigned*)&Pw[o] = pack2(f2bf(rg), f2bf(prt));
            }
        }
    }
    #pragma unroll
    for (int p2 = 0; p2 < 2; ++p2) {
        const int row = p2 * 8 + (lane >> 3);
        const int ch = (lane & 7) * 8;
        s16x8 vh = *(const s16x8*)&Pw[row * 72 + ch];
        const int nn = n0 + wv * 16 + row;
        const long o = ((long)(b * 2048 + nn)) * 512 + h * 64 + ch;
        *(s16x8*)(RGh + o) = vh;
    }
}

// ---------------------------------------------------------------------------
// Output projection: out = RG(bf16) @ Wo^T + bo. Direct-frag, no staging,
// no loop barriers. 32x128 tile, waves 2x2 (16x64).
// ---------------------------------------------------------------------------
__global__ __launch_bounds__(256, 2) void projo_kernel(
    const short* __restrict__ RGh, const short* __restrict__ Woh_g,
    const float* __restrict__ bo, float* __restrict__ out)
{
    __shared__ __align__(16) float TB[4 * 1168];

    const short* Wol_g = Woh_g + 262144;
    const int t = threadIdx.x, lane = t & 63, wv = t >> 6;
    const int wm = wv >> 1, wn = wv & 1;
    const int quad = lane >> 4, l15 = lane & 15;
    const int m0 = blockIdx.y * 32, n0 = blockIdx.x * 128;

    f32x4 acc[4];
    #pragma unroll
    for (int j = 0; j < 4; ++j) acc[j] = (f32x4){0.f, 0.f, 0.f, 0.f};

    const long abase = (long)(m0 + wm * 16 + l15) * 512 + quad * 8;
    const long bbase = (long)(n0 + wn * 64 + l15) * 512 + quad * 8;

    #pragma unroll 2
    for (int k0 = 0; k0 < 512; k0 += 32) {
        s16x8 ah, bh[4], bl[4];
        ah = *(const s16x8*)(RGh + abase + k0);
        #pragma unroll
        for (int s = 0; s < 4; ++s) {
            bh[s] = *(const s16x8*)(Woh_g + bbase + s * 16 * 512 + k0);
            bl[s] = *(const s16x8*)(Wol_g + bbase + s * 16 * 512 + k0);
        }
        #pragma unroll
        for (int j = 0; j < 4; ++j) {
            acc[j] = __builtin_amdgcn_mfma_f32_16x16x32_bf16(ah, bh[j], acc[j], 0, 0, 0);
            acc[j] = __builtin_amdgcn_mfma_f32_16x16x32_bf16(ah, bl[j], acc[j], 0, 0, 0);
        }
    }

    float* T = TB + wv * 1168;   // 16 x 73
    #pragma unroll
    for (int ns = 0; ns < 4; ++ns) {
        const int col = n0 + wn * 64 + ns * 16 + l15;
        const float bvv = bo[col];
        #pragma unroll
        for (int r = 0; r < 4; ++r)
            T[(quad * 4 + r) * 73 + ns * 16 + l15] = acc[ns][r] + bvv;
    }
    #pragma unroll
    for (int it = 0; it < 2; ++it) {
        const int row = it * 8 + (lane >> 3);
        const int ch = (lane & 7) * 8;
        f32x4 a = *(const f32x4*)&T[row * 73 + ch];
        f32x4 c = *(const f32x4*)&T[row * 73 + ch + 4];
        const long o = (long)(m0 + wm * 16 + row) * 512 + n0 + wn * 64 + ch;
        *(f32x4*)(out + o) = a;
        *(f32x4*)(out + o + 4) = c;
    }
}

extern "C" void kernel_launch(void* const* d_in, const int* in_sizes, int n_in,
                              void* d_out, int out_size, void* d_ws, size_t ws_size,
                              hipStream_t stream) {
    const float* query = (const float*)d_in[0];
    const float* kin   = (const float*)d_in[1];
    const float* vin   = (const float*)d_in[2];
    const float* Wq = (const float*)d_in[3];
    const float* bq = (const float*)d_in[4];
    const float* Wk = (const float*)d_in[5];
    const float* bk = (const float*)d_in[6];
    const float* Wv = (const float*)d_in[7];
    const float* bv = (const float*)d_in[8];
    const float* Wg = (const float*)d_in[9];
    const float* bg = (const float*)d_in[10];
    const float* Wo = (const float*)d_in[11];
    const float* bo = (const float*)d_in[12];

    short* S = (short*)d_ws;
    const long NE = 2097152;             // 4096*512 elements
    short* WSp = S;                      // 5 * 524288
    short* Xsp = S + 2621440;            // 3 * 4194304
    short* Qh  = Xsp + 12582912;
    short* Ql  = Qh + NE;
    short* Kh  = Ql + NE;
    short* Vth = Kh + NE;
    float* G   = (float*)(Vth + NE);
    short* RGh = (short*)(G + NE);

    presplit_kernel<<<1856, 256, 0, stream>>>(
        Wq, Wk, Wv, Wg, Wo, query, kin, vin, WSp, Xsp);
    projqkvg_kernel<<<dim3(4, 64, 4), 256, 0, stream>>>(
        Xsp, WSp, bq, bk, bv, bg, Qh, Ql, Kh, Vth, G);
    attn_kernel<<<dim3(32, 16), 256, 0, stream>>>(
        Qh, Ql, Kh, Vth, G, RGh);
    projo_kernel<<<dim3(4, 128), 256, 0, stream>>>(
        RGh, WSp + 4 * 524288, bo, (float*)d_out);
}

// Round 10
// 272.896 us; speedup vs baseline: 1.2805x; 1.2805x over previous
//
#include <hip/hip_runtime.h>
#include <math.h>

typedef float f32x4 __attribute__((ext_vector_type(4)));
typedef short s16x8 __attribute__((ext_vector_type(8)));
typedef short s16x4 __attribute__((ext_vector_type(4)));

__device__ __forceinline__ short f2bf(float f) {
    unsigned u = __builtin_bit_cast(unsigned, f);
    unsigned r = u + 0x7FFFu + ((u >> 16) & 1u);
    return (short)(r >> 16);
}
__device__ __forceinline__ float bf2f(short h) {
    return __builtin_bit_cast(float, ((unsigned)(unsigned short)h) << 16);
}
__device__ __forceinline__ unsigned pack2(short a, short b) {
    return (unsigned)(unsigned short)a | ((unsigned)(unsigned short)b << 16);
}

__device__ __forceinline__ void split16(const float* __restrict__ p,
                                        short* hi, short* lo) {
    f32x4 a0 = *(const f32x4*)(p);
    f32x4 a1 = *(const f32x4*)(p + 4);
    f32x4 a2 = *(const f32x4*)(p + 8);
    f32x4 a3 = *(const f32x4*)(p + 12);
    s16x8 h0, h1, l0, l1;
    #pragma unroll
    for (int i = 0; i < 4; ++i) {
        short h;
        h = f2bf(a0[i]); h0[i]     = h; l0[i]     = f2bf(a0[i] - bf2f(h));
        h = f2bf(a1[i]); h0[4 + i] = h; l0[4 + i] = f2bf(a1[i] - bf2f(h));
        h = f2bf(a2[i]); h1[i]     = h; l1[i]     = f2bf(a2[i] - bf2f(h));
        h = f2bf(a3[i]); h1[4 + i] = h; l1[4 + i] = f2bf(a3[i] - bf2f(h));
    }
    *(s16x8*)hi       = h0;
    *(s16x8*)(hi + 8) = h1;
    *(s16x8*)lo       = l0;
    *(s16x8*)(lo + 8) = l1;
}

// ---------------------------------------------------------------------------
// Pre-split 5 weight matrices AND the 3 activation inputs into hi/lo bf16.
// ---------------------------------------------------------------------------
__global__ __launch_bounds__(256) void presplit_kernel(
    const float* __restrict__ W0, const float* __restrict__ W1,
    const float* __restrict__ W2, const float* __restrict__ W3,
    const float* __restrict__ W4,
    const float* __restrict__ X0, const float* __restrict__ X1,
    const float* __restrict__ X2,
    short* __restrict__ Wsp, short* __restrict__ Xsp)
{
    const int blk = blockIdx.x;
    if (blk < 320) {
        const int w = blk >> 6, bi = blk & 63;
        const float* src = (w == 0) ? W0 : (w == 1) ? W1 : (w == 2) ? W2
                          : (w == 3) ? W3 : W4;
        short* hi = Wsp + (long)w * 524288;
        short* lo = hi + 262144;
        const int idx = (bi * 256 + threadIdx.x) * 16;
        split16(src + idx, hi + idx, lo + idx);
    } else {
        const int b2 = blk - 320;
        const int x = b2 >> 9, bi = b2 & 511;
        const float* src = (x == 0) ? X0 : (x == 1) ? X1 : X2;
        short* hi = Xsp + (long)x * 4194304;
        short* lo = hi + 2097152;
        const int idx = (bi * 256 + threadIdx.x) * 16;
        split16(src + idx, hi + idx, lo + idx);
    }
}

// ---------------------------------------------------------------------------
// Fused Q/K/V/G projections (round-8 structure: LDS staging + VGPR prefetch).
// 64x128 tile, 4 waves 2x2, BK=32.
// mode 0: Q rotary -> split [B,H,N,D]; 1: K rotary*0.125 -> hi [B,H,N,D];
// mode 2: V -> hi TRANSPOSED [B,H,D,N]; 3: G silu -> fp32 [B,N,E]
// ---------------------------------------------------------------------------
__global__ __launch_bounds__(256) void projqkvg_kernel(
    const short* __restrict__ Xsp, const short* __restrict__ Wsp,
    const float* __restrict__ bq, const float* __restrict__ bk,
    const float* __restrict__ bv, const float* __restrict__ bg,
    short* __restrict__ Qh, short* __restrict__ Ql,
    short* __restrict__ Kh, short* __restrict__ Vth,
    float* __restrict__ G)
{
    __shared__ __align__(16) short SB[15360];   // 30 KB
    short* XhS = SB;            // 64*40
    short* XlS = SB + 2560;
    short* WhS = SB + 5120;     // 128*40
    short* WlS = SB + 10240;

    const int mode = blockIdx.z;
    const int xi = (mode == 1) ? 1 : (mode == 2) ? 2 : 0;
    const short* Xh_g = Xsp + (long)xi * 4194304;
    const short* Xl_g = Xh_g + 2097152;
    const short* Wh_g = Wsp + (long)mode * 524288;
    const short* Wl_g = Wh_g + 262144;
    const float* bias = (mode == 0) ? bq : (mode == 1) ? bk
                       : (mode == 2) ? bv : bg;

    const int t = threadIdx.x, lane = t & 63, wv = t >> 6;
    const int wm = wv >> 1, wn = wv & 1;
    const int quad = lane >> 4, l15 = lane & 15;
    const int m0 = blockIdx.y * 64, n0 = blockIdx.x * 128;

    f32x4 acc[2][4];
    #pragma unroll
    for (int i = 0; i < 2; ++i)
        #pragma unroll
        for (int j = 0; j < 4; ++j)
            acc[i][j] = (f32x4){0.f, 0.f, 0.f, 0.f};

    const int xrow = t >> 2, xcol = (t & 3) * 8;
    const int wrow = t >> 1, wcol = (t & 1) * 16;
    const long xbase = (long)(m0 + xrow) * 512 + xcol;
    const long wbase = (long)(n0 + wrow) * 512 + wcol;

    s16x8 pxh, pxl, pwh0, pwh1, pwl0, pwl1;
    pxh  = *(const s16x8*)(Xh_g + xbase);
    pxl  = *(const s16x8*)(Xl_g + xbase);
    pwh0 = *(const s16x8*)(Wh_g + wbase);
    pwh1 = *(const s16x8*)(Wh_g + wbase + 8);
    pwl0 = *(const s16x8*)(Wl_g + wbase);
    pwl1 = *(const s16x8*)(Wl_g + wbase + 8);

    for (int k0 = 0; k0 < 512; k0 += 32) {
        __syncthreads();
        *(s16x8*)&XhS[xrow * 40 + xcol]     = pxh;
        *(s16x8*)&XlS[xrow * 40 + xcol]     = pxl;
        *(s16x8*)&WhS[wrow * 40 + wcol]     = pwh0;
        *(s16x8*)&WhS[wrow * 40 + wcol + 8] = pwh1;
        *(s16x8*)&WlS[wrow * 40 + wcol]     = pwl0;
        *(s16x8*)&WlS[wrow * 40 + wcol + 8] = pwl1;
        __syncthreads();

        if (k0 + 32 < 512) {
            const long xo = xbase + k0 + 32;
            const long wo = wbase + k0 + 32;
            pxh  = *(const s16x8*)(Xh_g + xo);
            pxl  = *(const s16x8*)(Xl_g + xo);
            pwh0 = *(const s16x8*)(Wh_g + wo);
            pwh1 = *(const s16x8*)(Wh_g + wo + 8);
            pwl0 = *(const s16x8*)(Wl_g + wo);
            pwl1 = *(const s16x8*)(Wl_g + wo + 8);
        }

        s16x8 ah[2], al[2], bh[4], bl[4];
        #pragma unroll
        for (int s = 0; s < 2; ++s) {
            const int ro = (wm * 32 + s * 16 + l15) * 40 + quad * 8;
            ah[s] = *(const s16x8*)&XhS[ro];
            al[s] = *(const s16x8*)&XlS[ro];
        }
        #pragma unroll
        for (int s = 0; s < 4; ++s) {
            const int ro = (wn * 64 + s * 16 + l15) * 40 + quad * 8;
            bh[s] = *(const s16x8*)&WhS[ro];
            bl[s] = *(const s16x8*)&WlS[ro];
        }
        #pragma unroll
        for (int i = 0; i < 2; ++i)
            #pragma unroll
            for (int j = 0; j < 4; ++j) {
                acc[i][j] = __builtin_amdgcn_mfma_f32_16x16x32_bf16(ah[i], bh[j], acc[i][j], 0, 0, 0);
                acc[i][j] = __builtin_amdgcn_mfma_f32_16x16x32_bf16(al[i], bh[j], acc[i][j], 0, 0, 0);
                acc[i][j] = __builtin_amdgcn_mfma_f32_16x16x32_bf16(ah[i], bl[j], acc[i][j], 0, 0, 0);
            }
    }

    __syncthreads();   // staging reads done; LDS reusable

    const int bb = m0 >> 11, posb = m0 & 2047;

    if (mode == 0) {
        short* Thi = SB + wv * 2304;
        short* Tlo = Thi + 1152;
        const int hcol = (n0 >> 6) + wn;
        #pragma unroll
        for (int ms = 0; ms < 2; ++ms) {
            #pragma unroll
            for (int ns = 0; ns < 4; ++ns) {
                const int col = n0 + wn * 64 + ns * 16 + l15;
                const float bvv = bias[col];
                const int pp = (col & 63) >> 1;
                const float theta = powf(10000.0f, -(float)pp * (1.0f / 31.0f));
                #pragma unroll
                for (int r = 0; r < 4; ++r) {
                    const int m = m0 + wm * 32 + ms * 16 + quad * 4 + r;
                    const int pos = m & 2047;
                    float x = acc[ms][ns][r] + bvv;
                    float prt = __shfl_xor(x, 1);
                    float ang = (float)pos * theta;
                    float sv = sinf(ang), cv = cosf(ang);
                    float y0 = x * cv - prt * sv;
                    float y1 = prt * cv + x * sv;
                    if (!(l15 & 1)) {
                        short h0 = f2bf(y0), h1 = f2bf(y1);
                        short l0 = f2bf(y0 - bf2f(h0)), l1 = f2bf(y1 - bf2f(h1));
                        const int o = (quad * 4 + r) * 72 + ns * 16 + l15;
                        *(unsigned*)&Thi[o] = pack2(h0, h1);
                        *(unsigned*)&Tlo[o] = pack2(l0, l1);
                    }
                }
            }
            const int mrow = wm * 32 + ms * 16;
            #pragma unroll
            for (int p2 = 0; p2 < 2; ++p2) {
                const int row = p2 * 8 + (lane >> 3);
                const int ch = (lane & 7) * 8;
                s16x8 vh = *(const s16x8*)&Thi[row * 72 + ch];
                s16x8 vl = *(const s16x8*)&Tlo[row * 72 + ch];
                const long o = ((long)(bb * 8 + hcol) * 2048 + posb + mrow + row) * 64 + ch;
                *(s16x8*)(Qh + o) = vh;
                *(s16x8*)(Ql + o) = vl;
            }
        }
    } else if (mode == 1) {
        short* Thi = SB + wv * 1152;
        const int hcol = (n0 >> 6) + wn;
        #pragma unroll
        for (int ms = 0; ms < 2; ++ms) {
            #pragma unroll
            for (int ns = 0; ns < 4; ++ns) {
                const int col = n0 + wn * 64 + ns * 16 + l15;
                const float bvv = bias[col];
                const int pp = (col & 63) >> 1;
                const float theta = powf(10000.0f, -(float)pp * (1.0f / 31.0f));
                #pragma unroll
                for (int r = 0; r < 4; ++r) {
                    const int m = m0 + wm * 32 + ms * 16 + quad * 4 + r;
                    const int pos = m & 2047;
                    float x = acc[ms][ns][r] + bvv;
                    float prt = __shfl_xor(x, 1);
                    float ang = (float)pos * theta;
                    float sv = sinf(ang), cv = cosf(ang);
                    float y0 = (x * cv - prt * sv) * 0.125f;
                    float y1 = (prt * cv + x * sv) * 0.125f;
                    if (!(l15 & 1)) {
                        const int o = (quad * 4 + r) * 72 + ns * 16 + l15;
                        *(unsigned*)&Thi[o] = pack2(f2bf(y0), f2bf(y1));
                    }
                }
            }
            const int mrow = wm * 32 + ms * 16;
            #pragma unroll
            for (int p2 = 0; p2 < 2; ++p2) {
                const int row = p2 * 8 + (lane >> 3);
                const int ch = (lane & 7) * 8;
                s16x8 vh = *(const s16x8*)&Thi[row * 72 + ch];
                const long o = ((long)(bb * 8 + hcol) * 2048 + posb + mrow + row) * 64 + ch;
                *(s16x8*)(Kh + o) = vh;
            }
        }
    } else if (mode == 2) {
        short* T2 = SB;   // 128 x 72
        #pragma unroll
        for (int ns = 0; ns < 4; ++ns) {
            const int col = n0 + wn * 64 + ns * 16 + l15;
            const float bvv = bias[col];
            #pragma unroll
            for (int ms = 0; ms < 2; ++ms) {
                s16x4 pk;
                #pragma unroll
                for (int r = 0; r < 4; ++r)
                    pk[r] = f2bf(acc[ms][ns][r] + bvv);
                *(s16x4*)&T2[(wn * 64 + ns * 16 + l15) * 72
                             + wm * 32 + ms * 16 + quad * 4] = pk;
            }
        }
        __syncthreads();
        #pragma unroll
        for (int pass = 0; pass < 4; ++pass) {
            const int row = pass * 32 + (t >> 3);
            const int ch = (t & 7) * 8;
            s16x8 v = *(const s16x8*)&T2[row * 72 + ch];
            const int head = (n0 >> 6) + (row >> 6);
            const int d = row & 63;
            const long o = ((long)(bb * 8 + head) * 64 + d) * 2048 + posb + ch;
            *(s16x8*)(Vth + o) = v;
        }
    } else {
        #pragma unroll
        for (int ns = 0; ns < 4; ++ns) {
            const int col = n0 + wn * 64 + ns * 16 + l15;
            const float bvv = bias[col];
            #pragma unroll
            for (int ms = 0; ms < 2; ++ms)
                #pragma unroll
                for (int r = 0; r < 4; ++r) {
                    const int m = m0 + wm * 32 + ms * 16 + quad * 4 + r;
                    float x = acc[ms][ns][r] + bvv;
                    G[(long)m * 512 + col] = x / (1.0f + expf(-x));
                }
        }
    }
}

// ---------------------------------------------------------------------------
// Retention attention: double-buffered K/V LDS, ONE barrier per s-tile.
// Per iter: [ds_write regs->buf] [sync] [issue next loads] [QK+PV from buf].
// Safe: a wave writes buf only after the barrier that followed all waves'
// reads of that buffer (2 iterations ago).
// K,V,P bf16 hi; Q split. Decay cutoff. RG single bf16 plane, coalesced.
// ---------------------------------------------------------------------------
__global__ __launch_bounds__(256) void attn_kernel(
    const short* __restrict__ Qh_g, const short* __restrict__ Ql_g,
    const short* __restrict__ Kh_g, const short* __restrict__ Vth_g,
    const float* __restrict__ G,
    short* __restrict__ RGh)
{
    __shared__ __align__(16) short KhS[2][64 * 72], VhS[2][64 * 72];
    __shared__ __align__(16) short PhS[64 * 68];

    const int t = threadIdx.x, lane = t & 63, wv = t >> 6;
    const int quad = lane >> 4, l15 = lane & 15;
    const int bh = blockIdx.y, h = bh & 7, b = bh >> 3;
    const int qt = (bh & 1) ? blockIdx.x : (31 - blockIdx.x);
    const int n0 = qt * 64;
    const long base = (long)bh * 2048 * 64;

    float l2g;
    int stLo;
    {
        float lg0 = logf(1.0f / 32.0f), lg1 = logf(1.0f / 512.0f);
        float om = expf(lg0 + (float)h * (lg1 - lg0) * (1.0f / 7.0f));
        l2g = log2f(1.0f - om);
        int Dcut = (int)(11.5129255f / om) + 64;
        stLo = (n0 - Dcut) >> 6;
        if (stLo < 0) stLo = 0;
    }
    float gneg[16];
    #pragma unroll
    for (int i = 0; i < 16; ++i)
        gneg[i] = exp2f(-(float)((i >> 2) * 16 + (i & 3)) * l2g);

    const int srow = t >> 2;
    const int scol = (t & 3) * 16;
    const int n = n0 + wv * 16 + l15;

    s16x8 qh[2], ql[2];
    {
        const long qo = base + (long)(n0 + wv * 16 + l15) * 64 + quad * 8;
        qh[0] = *(const s16x8*)(Qh_g + qo);
        qh[1] = *(const s16x8*)(Qh_g + qo + 32);
        ql[0] = *(const s16x8*)(Ql_g + qo);
        ql[1] = *(const s16x8*)(Ql_g + qo + 32);
    }

    f32x4 racc[4];
    #pragma unroll
    for (int i = 0; i < 4; ++i) racc[i] = (f32x4){0.f, 0.f, 0.f, 0.f};

    // prologue prefetch of tile stLo into regs
    s16x8 pk0, pk1, pv0, pv1;
    {
        const long ko = base + (long)(stLo * 64 + srow) * 64 + scol;
        pk0 = *(const s16x8*)(Kh_g + ko);
        pk1 = *(const s16x8*)(Kh_g + ko + 8);
        const long vo = base + (long)srow * 2048 + stLo * 64 + scol;
        pv0 = *(const s16x8*)(Vth_g + vo);
        pv1 = *(const s16x8*)(Vth_g + vo + 8);
    }

    int buf = 0;
    for (int st = stLo; st <= qt; ++st) {
        const int s0 = st * 64;

        // commit prefetched tile into current buffer (waits vmcnt)
        *(s16x8*)&KhS[buf][srow * 72 + scol]     = pk0;
        *(s16x8*)&KhS[buf][srow * 72 + scol + 8] = pk1;
        *(s16x8*)&VhS[buf][srow * 72 + scol]     = pv0;
        *(s16x8*)&VhS[buf][srow * 72 + scol + 8] = pv1;
        __syncthreads();   // the ONLY barrier per tile

        // issue next tile's loads (overlap with compute below)
        if (st < qt) {
            const long ko = base + (long)(s0 + 64 + srow) * 64 + scol;
            pk0 = *(const s16x8*)(Kh_g + ko);
            pk1 = *(const s16x8*)(Kh_g + ko + 8);
            const long vo = base + (long)srow * 2048 + s0 + 64 + scol;
            pv0 = *(const s16x8*)(Vth_g + vo);
            pv1 = *(const s16x8*)(Vth_g + vo + 8);
        }

        const float t0 = exp2f((float)(n - s0 - quad * 4) * l2g);

        #pragma unroll
        for (int sub = 0; sub < 4; ++sub) {
            const int ro = (sub * 16 + l15) * 72 + quad * 8;
            s16x8 kh0 = *(const s16x8*)&KhS[buf][ro];
            s16x8 kh1 = *(const s16x8*)&KhS[buf][ro + 32];
            f32x4 sacc = (f32x4){0.f, 0.f, 0.f, 0.f};
            sacc = __builtin_amdgcn_mfma_f32_16x16x32_bf16(kh0, qh[0], sacc, 0, 0, 0);
            sacc = __builtin_amdgcn_mfma_f32_16x16x32_bf16(kh1, qh[1], sacc, 0, 0, 0);
            sacc = __builtin_amdgcn_mfma_f32_16x16x32_bf16(kh0, ql[0], sacc, 0, 0, 0);
            sacc = __builtin_amdgcn_mfma_f32_16x16x32_bf16(kh1, ql[1], sacc, 0, 0, 0);

            const int sb = s0 + sub * 16 + quad * 4;
            s16x4 pkh;
            #pragma unroll
            for (int r = 0; r < 4; ++r) {
                const int s = sb + r;
                const float wgt = (n >= s) ? t0 * gneg[sub * 4 + r] : 0.0f;
                pkh[r] = f2bf(sacc[r] * wgt);
            }
            *(s16x4*)&PhS[(wv * 16 + l15) * 68 + sub * 16 + quad * 4] = pkh;
        }

        const int pro = (wv * 16 + l15) * 68 + quad * 8;
        s16x8 ph0 = *(const s16x8*)&PhS[pro];
        s16x8 ph1 = *(const s16x8*)&PhS[pro + 32];
        #pragma unroll
        for (int ds = 0; ds < 4; ++ds) {
            const int ro = (ds * 16 + l15) * 72 + quad * 8;
            s16x8 vh0 = *(const s16x8*)&VhS[buf][ro];
            s16x8 vh1 = *(const s16x8*)&VhS[buf][ro + 32];
            racc[ds] = __builtin_amdgcn_mfma_f32_16x16x32_bf16(ph0, vh0, racc[ds], 0, 0, 0);
            racc[ds] = __builtin_amdgcn_mfma_f32_16x16x32_bf16(ph1, vh1, racc[ds], 0, 0, 0);
        }
        buf ^= 1;
    }

    float mean[4], rstd[4];
    #pragma unroll
    for (int r = 0; r < 4; ++r) {
        float s = racc[0][r] + racc[1][r] + racc[2][r] + racc[3][r];
        s += __shfl_xor(s, 1); s += __shfl_xor(s, 2);
        s += __shfl_xor(s, 4); s += __shfl_xor(s, 8);
        mean[r] = s * (1.0f / 64.0f);
        float vs = 0.f;
        #pragma unroll
        for (int ds = 0; ds < 4; ++ds) {
            float d = racc[ds][r] - mean[r];
            vs += d * d;
        }
        vs += __shfl_xor(vs, 1); vs += __shfl_xor(vs, 2);
        vs += __shfl_xor(vs, 4); vs += __shfl_xor(vs, 8);
        rstd[r] = rsqrtf(vs * (1.0f / 64.0f) + 1e-6f);
    }

    __syncthreads();   // everyone done with LDS buffers; reuse for RG
    short* rgH = &KhS[0][wv * 1152];
    #pragma unroll
    for (int ds = 0; ds < 4; ++ds) {
        #pragma unroll
        for (int r = 0; r < 4; ++r) {
            const int nn = n0 + wv * 16 + quad * 4 + r;
            const int d = ds * 16 + l15;
            const long gi = ((long)(b * 2048 + nn)) * 512 + h * 64 + d;
            float rg = (racc[ds][r] - mean[r]) * rstd[r] * G[gi];
            float prt = __shfl_xor(rg, 1);
            if (!(l15 & 1)) {
                const int o = (quad * 4 + r) * 72 + ds * 16 + l15;
                *(unsigned*)&rgH[o] = pack2(f2bf(rg), f2bf(prt));
            }
        }
    }
    #pragma unroll
    for (int p2 = 0; p2 < 2; ++p2) {
        const int row = p2 * 8 + (lane >> 3);
        const int ch = (lane & 7) * 8;
        s16x8 vh = *(const s16x8*)&rgH[row * 72 + ch];
        const int nn = n0 + wv * 16 + row;
        const long o = ((long)(b * 2048 + nn)) * 512 + h * 64 + ch;
        *(s16x8*)(RGh + o) = vh;
    }
}

// ---------------------------------------------------------------------------
// Output projection: out = RG(bf16) @ Wo^T + bo. 32x128 tile, waves 2x2.
// LDS staging + VGPR prefetch (round-8 structure).
// ---------------------------------------------------------------------------
__global__ __launch_bounds__(256) void projo_kernel(
    const short* __restrict__ RGh, const short* __restrict__ Woh_g,
    const float* __restrict__ bo, float* __restrict__ out)
{
    __shared__ __align__(16) char PB[23040];
    short* XhS = (short*)PB;            // 32*40
    short* WhS = XhS + 1280;            // 128*40
    short* WlS = XhS + 6400;

    const short* Wol_g = Woh_g + 262144;
    const int t = threadIdx.x, lane = t & 63, wv = t >> 6;
    const int wm = wv >> 1, wn = wv & 1;
    const int quad = lane >> 4, l15 = lane & 15;
    const int m0 = blockIdx.y * 32, n0 = blockIdx.x * 128;

    f32x4 acc[4];
    #pragma unroll
    for (int j = 0; j < 4; ++j) acc[j] = (f32x4){0.f, 0.f, 0.f, 0.f};

    const int xrow = t >> 3, xcol = (t & 7) * 4;
    const int wrow = t >> 1, wcol = (t & 1) * 16;
    const long xbase = (long)(m0 + xrow) * 512 + xcol;
    const long wbase = (long)(n0 + wrow) * 512 + wcol;

    s16x4 px;
    s16x8 pw0, pw1, pw2, pw3;
    px  = *(const s16x4*)(RGh + xbase);
    pw0 = *(const s16x8*)(Woh_g + wbase);
    pw1 = *(const s16x8*)(Woh_g + wbase + 8);
    pw2 = *(const s16x8*)(Wol_g + wbase);
    pw3 = *(const s16x8*)(Wol_g + wbase + 8);

    for (int k0 = 0; k0 < 512; k0 += 32) {
        __syncthreads();
        *(s16x4*)&XhS[xrow * 40 + xcol]     = px;
        *(s16x8*)&WhS[wrow * 40 + wcol]     = pw0;
        *(s16x8*)&WhS[wrow * 40 + wcol + 8] = pw1;
        *(s16x8*)&WlS[wrow * 40 + wcol]     = pw2;
        *(s16x8*)&WlS[wrow * 40 + wcol + 8] = pw3;
        __syncthreads();

        if (k0 + 32 < 512) {
            const long xo = xbase + k0 + 32;
            const long wo = wbase + k0 + 32;
            px  = *(const s16x4*)(RGh + xo);
            pw0 = *(const s16x8*)(Woh_g + wo);
            pw1 = *(const s16x8*)(Woh_g + wo + 8);
            pw2 = *(const s16x8*)(Wol_g + wo);
            pw3 = *(const s16x8*)(Wol_g + wo + 8);
        }

        s16x8 ah, bh[4], bl[4];
        {
            const int ro = (wm * 16 + l15) * 40 + quad * 8;
            ah = *(const s16x8*)&XhS[ro];
        }
        #pragma unroll
        for (int s = 0; s < 4; ++s) {
            const int ro = (wn * 64 + s * 16 + l15) * 40 + quad * 8;
            bh[s] = *(const s16x8*)&WhS[ro];
            bl[s] = *(const s16x8*)&WlS[ro];
        }
        #pragma unroll
        for (int j = 0; j < 4; ++j) {
            acc[j] = __builtin_amdgcn_mfma_f32_16x16x32_bf16(ah, bh[j], acc[j], 0, 0, 0);
            acc[j] = __builtin_amdgcn_mfma_f32_16x16x32_bf16(ah, bl[j], acc[j], 0, 0, 0);
        }
    }

    __syncthreads();
    float* T = (float*)PB + wv * 1152;   // 16 x 72 fp32
    #pragma unroll
    for (int ns = 0; ns < 4; ++ns) {
        const int col = n0 + wn * 64 + ns * 16 + l15;
        const float bvv = bo[col];
        #pragma unroll
        for (int r = 0; r < 4; ++r)
            T[(quad * 4 + r) * 72 + ns * 16 + l15] = acc[ns][r] + bvv;
    }
    #pragma unroll
    for (int it = 0; it < 2; ++it) {
        const int row = it * 8 + (lane >> 3);
        const int ch = (lane & 7) * 8;
        f32x4 a = *(const f32x4*)&T[row * 72 + ch];
        f32x4 c = *(const f32x4*)&T[row * 72 + ch + 4];
        const long o = (long)(m0 + wm * 16 + row) * 512 + n0 + wn * 64 + ch;
        *(f32x4*)(out + o) = a;
        *(f32x4*)(out + o + 4) = c;
    }
}

extern "C" void kernel_launch(void* const* d_in, const int* in_sizes, int n_in,
                              void* d_out, int out_size, void* d_ws, size_t ws_size,
                              hipStream_t stream) {
    const float* query = (const float*)d_in[0];
    const float* kin   = (const float*)d_in[1];
    const float* vin   = (const float*)d_in[2];
    const float* Wq = (const float*)d_in[3];
    const float* bq = (const float*)d_in[4];
    const float* Wk = (const float*)d_in[5];
    const float* bk = (const float*)d_in[6];
    const float* Wv = (const float*)d_in[7];
    const float* bv = (const float*)d_in[8];
    const float* Wg = (const float*)d_in[9];
    const float* bg = (const float*)d_in[10];
    const float* Wo = (const float*)d_in[11];
    const float* bo = (const float*)d_in[12];

    short* S = (short*)d_ws;
    const long NE = 2097152;             // 4096*512 elements
    short* WSp = S;                      // 5 * 524288
    short* Xsp = S + 2621440;            // 3 * 4194304
    short* Qh  = Xsp + 12582912;
    short* Ql  = Qh + NE;
    short* Kh  = Ql + NE;
    short* Vth = Kh + NE;
    float* G   = (float*)(Vth + NE);
    short* RGh = (short*)(G + NE);

    presplit_kernel<<<1856, 256, 0, stream>>>(
        Wq, Wk, Wv, Wg, Wo, query, kin, vin, WSp, Xsp);
    projqkvg_kernel<<<dim3(4, 64, 4), 256, 0, stream>>>(
        Xsp, WSp, bq, bk, bv, bg, Qh, Ql, Kh, Vth, G);
    attn_kernel<<<dim3(32, 16), 256, 0, stream>>>(
        Qh, Ql, Kh, Vth, G, RGh);
    projo_kernel<<<dim3(4, 128), 256, 0, stream>>>(
        RGh, WSp + 4 * 524288, bo, (float*)d_out);
}